// Round 8
// baseline (212.220 us; speedup 1.0000x reference)
//
#include <hip/hip_runtime.h>
#include <cmath>

#define NPTS 4096
#define NPOINT 204   // int(4096 * 0.05)
#define NPCT 5
#define MAXNS 409    // int(4096 * 0.10)
#define FPS_T 512    // threads per block (8 waves)
#define NGROUP 408   // B * NPOINT
#define NPART (NGROUP * NPCT)
#define MAXSLOT 7    // ceil(409/64)
#define NWAVE 8      // waves per block

// fused-launch geometry: 2 FPS blocks + 510 worker blocks = 512 blocks,
// ~66 KB LDS -> 2 blocks/CU x 256 CUs, all co-resident (R6-proven, best
// measured: fused 135.0 / total 185.2). R7's 1-block/CU + finisher variant
// regressed (150.4) and is reverted.
#define NWORK  510
#define NROUND 4     // 510 * 4 = 2040 = NPART

// shared-memory union layout (bytes). SMEM kept in the same 66048 LDS
// granule as R6 so occupancy/placement are byte-identical; fps no longer
// uses the 64 KB pts region (payload-xyz carries the winner's coords).
#define SMEM_BYTES 65920
#define KEYS_OFF   65536          // fps: keys u64[2][8] (128 B)
#define PAYL_OFF   65664          // fps: payload float4[2][8] (256 B)
#define WRES_OFF   6544           // grp: gpts float4[409] = 6544
#define WTOT_OFF   35216          //      wres float2[8][7][64] = 28672
#define SPART_OFF  35248          //      s_wtot int[8]
#define SQI_OFF    35280          //      s_part float[8]

typedef unsigned long long u64;
typedef float f32x2 __attribute__((ext_vector_type(2)));

struct LossParams {
    int   nsample[NPCT];
    float r2[NPCT];
    float wscale[NPCT];   // (p*100)^2 / (B*NPOINT*NPCT)
    float expect_len;
};

// ---------------- DPP wave64 reductions ------------------------------------
template <int CTRL>
__device__ __forceinline__ int dpp_imax(int v) {
    int t = __builtin_amdgcn_update_dpp(0, v, CTRL, 0xf, 0xf, true);
    return v > t ? v : t;
}
template <int CTRL>
__device__ __forceinline__ int dpp_imin(int v) {
    int t = __builtin_amdgcn_update_dpp(0x7fffffff, v, CTRL, 0xf, 0xf, false);
    return v < t ? v : t;
}
__device__ __forceinline__ int wave_max_i(int v) {
    v = dpp_imax<0x111>(v); v = dpp_imax<0x112>(v);
    v = dpp_imax<0x114>(v); v = dpp_imax<0x118>(v);
    v = dpp_imax<0x142>(v); v = dpp_imax<0x143>(v);
    return __builtin_amdgcn_readlane(v, 63);
}
__device__ __forceinline__ int wave_min_i(int v) {
    v = dpp_imin<0x111>(v); v = dpp_imin<0x112>(v);
    v = dpp_imin<0x114>(v); v = dpp_imin<0x118>(v);
    v = dpp_imin<0x142>(v); v = dpp_imin<0x143>(v);
    return __builtin_amdgcn_readlane(v, 63);
}
template <int CTRL>
__device__ __forceinline__ u64 dpp_u64max(u64 v) {
    int lo = (int)(unsigned)v;
    int hi = (int)(unsigned)(v >> 32);
    unsigned slo = (unsigned)__builtin_amdgcn_update_dpp(0, lo, CTRL, 0xf, 0xf, true);
    unsigned shi = (unsigned)__builtin_amdgcn_update_dpp(0, hi, CTRL, 0xf, 0xf, true);
    u64 o = ((u64)shi << 32) | slo;
    return v > o ? v : o;
}

// ---------------------------------------------------------------------------
// FPS role — R6 algorithm with ONE structural change: the winner's xyz is
// carried through the argmax (scan keeps bx,by,bz; winning lane deposits
// key+payload to LDS; coords recovered post-reduce via 3 v_readlane),
// removing the dependent pts[last] LDS read (~120-200 cy) from the serial
// chain each iteration. pts[] is then never read -> its writes are dropped.
// Key low word packs ~(idx<<3|wave); idx is globally unique so selected
// indices are bit-identical to R6.
// ---------------------------------------------------------------------------
__device__ void fps_role(const float* __restrict__ pcd,
                         int* __restrict__ fps_idx,
                         char* smem) {
#pragma clang fp contract(off)
    __builtin_amdgcn_s_setprio(3);
    u64 (*keys)[NWAVE] = reinterpret_cast<u64 (*)[NWAVE]>(smem + KEYS_OFF);
    float4 (*payl)[NWAVE] = reinterpret_cast<float4 (*)[NWAVE]>(smem + PAYL_OFF);

    const int b = blockIdx.x;
    const int t = threadIdx.x;
    const int wave = t >> 6, lane = t & 63;
    const float* base = pcd + (size_t)b * NPTS * 3;

    f32x2 X[4], Y[4], Z[4], D[4];
    #pragma unroll
    for (int q = 0; q < 4; ++q) {
        int n0 = (2 * q) * FPS_T + t;
        int n1 = (2 * q + 1) * FPS_T + t;
        float x0 = base[3 * n0 + 0], y0 = base[3 * n0 + 1], z0 = base[3 * n0 + 2];
        float x1 = base[3 * n1 + 0], y1 = base[3 * n1 + 1], z1 = base[3 * n1 + 2];
        X[q] = (f32x2){x0, x1};
        Y[q] = (f32x2){y0, y1};
        Z[q] = (f32x2){z0, z1};
        D[q] = (f32x2){1e10f, 1e10f};
    }
    int* out = fps_idx + b * NPOINT;
    if (t == 0)
        __hip_atomic_store(&out[0], 0, __ATOMIC_RELAXED, __HIP_MEMORY_SCOPE_AGENT);
    // initial centroid = point 0 (uniform broadcast read, one time)
    float cx = base[0], cy = base[1], cz = base[2];
    __syncthreads();

    for (int it = 1; it < NPOINT; ++it) {
        f32x2 cxx = (f32x2){cx, cx};
        f32x2 cyy = (f32x2){cy, cy};
        f32x2 czz = (f32x2){cz, cz};
        int bb = -1, bi = 0;
        float bx = 0.0f, by = 0.0f, bz = 0.0f;
        #pragma unroll
        for (int q = 0; q < 4; ++q) {
            f32x2 dx = X[q] - cxx, dy = Y[q] - cyy, dz = Z[q] - czz;
            f32x2 d  = (dx * dx + dy * dy) + dz * dz;
            f32x2 dd = D[q];
            float d0 = fminf(dd.x, d.x);
            float d1 = fminf(dd.y, d.y);
            D[q] = (f32x2){d0, d1};
            int b0 = __float_as_int(d0);
            int b1 = __float_as_int(d1);
            if (b0 > bb) { bb = b0; bi = (2 * q) * FPS_T + t;
                           bx = X[q].x; by = Y[q].x; bz = Z[q].x; }
            if (b1 > bb) { bb = b1; bi = (2 * q + 1) * FPS_T + t;
                           bx = X[q].y; by = Y[q].y; bz = Z[q].y; }
        }
        int wmax = wave_max_i(bb);
        int cand = (bb == wmax) ? bi : 0x7fffffff;
        int widx = wave_min_i(cand);
        // unique winning lane deposits key + coordinate payload
        if (bb == wmax && bi == widx) {
            keys[it & 1][wave] =
                ((u64)(unsigned)wmax << 32) |
                (unsigned)~(unsigned)((widx << 3) | wave);
            payl[it & 1][wave] = make_float4(bx, by, bz, 0.0f);
        }
        // LDS-only barrier (keys/payload visibility needs lgkmcnt only)
        asm volatile("s_waitcnt lgkmcnt(0)" ::: "memory");
        __builtin_amdgcn_s_barrier();
        u64 kv = keys[it & 1][lane & 7];     // 8 wave-keys
        float4 pw = payl[it & 1][lane & 7];  // parallel read, same latency window
        kv = dpp_u64max<0x111>(kv);
        kv = dpp_u64max<0x112>(kv);
        kv = dpp_u64max<0x114>(kv);
        unsigned lo7 = (unsigned)__builtin_amdgcn_readlane((int)(unsigned)kv, 7);
        unsigned un = ~lo7;
        int last = (int)(un >> 3);
        int wv   = (int)(un & 7u);
        cx = __int_as_float(__builtin_amdgcn_readlane(__float_as_int(pw.x), wv));
        cy = __int_as_float(__builtin_amdgcn_readlane(__float_as_int(pw.y), wv));
        cz = __int_as_float(__builtin_amdgcn_readlane(__float_as_int(pw.z), wv));
        if (t == 0)
            __hip_atomic_store(&out[it], last, __ATOMIC_RELAXED, __HIP_MEMORY_SCOPE_AGENT);
    }
}

// ---- Phase B worker: K i-slots/lane, j streamed over this wave's eighth ---
// min2 (smallest two incl. self) tracking via med3; exact reference k=2 KNN.
template <int K>
__device__ __forceinline__ void phaseB(const float4* __restrict__ gpts,
                                       float2 (*wres)[64],   // [MAXSLOT][64], this wave's slab
                                       int j0, int j1, int lane, int cntB) {
    float4 pi[K];
    float m1[K], m2[K];
    #pragma unroll
    for (int s = 0; s < K; ++s) {
        int idx = s * 64 + lane;
        pi[s] = gpts[idx < cntB ? idx : 0];   // dummy lanes skipped at merge
        m1[s] = 1e30f; m2[s] = 1e30f;
    }
    #pragma unroll 2
    for (int j = j0; j < j1; ++j) {
        float4 a = gpts[j];                   // wave-uniform broadcast read
        #pragma unroll
        for (int s = 0; s < K; ++s) {
            float tt = pi[s].x * a.x;
            tt = fmaf(pi[s].y, a.y, tt);
            tt = fmaf(pi[s].z, a.z, tt);
            float h = fmaf(-2.0f, tt, a.w);   // |a|^2 - 2<pi,a>
            m2[s] = __builtin_amdgcn_fmed3f(m1[s], m2[s], h);
            m1[s] = fminf(m1[s], h);
        }
    }
    #pragma unroll
    for (int s = 0; s < K; ++s) wres[s][lane] = (float2){m1[s], m2[s]};
}

// exact min2 merge of two (m1,m2) pairs — pure selection, no rounding
__device__ __forceinline__ float2 min2merge(float2 a, float2 b) {
    return (float2){fminf(a.x, b.x),
                    fminf(fmaxf(a.x, b.x), fminf(a.y, b.y))};
}

// ---------------------------------------------------------------------------
// Worker role: R6-proven static assignment, tau = w + round*510 (ascending m
// -> tasks unlock progressively while FPS runs). Byte-identical to R6.
// ---------------------------------------------------------------------------
__device__ void worker_role(const float* __restrict__ pcd,
                            int* __restrict__ fps_idx,
                            float* __restrict__ partials,
                            const LossParams& P, char* smem) {
    float4* gpts = reinterpret_cast<float4*>(smem);
    auto wres    = reinterpret_cast<float2 (*)[MAXSLOT][64]>(smem + WRES_OFF);
    int*   s_wtot = reinterpret_cast<int*>(smem + WTOT_OFF);
    float* s_part = reinterpret_cast<float*>(smem + SPART_OFF);
    int*   s_qi   = reinterpret_cast<int*>(smem + SQI_OFF);

    const int w = blockIdx.x - 2;
    const int t = threadIdx.x;
    const int wave = t >> 6, lane = t & 63;

    for (int round = 0; round < NROUND; ++round) {
        const int tau  = w + round * NWORK;          // 0 .. NPART-1, each once
        const int m_   = tau / 10;                   // group row (unlock order)
        const int rem  = tau - m_ * 10;
        const int b    = rem / 5;
        const int pidx = rem - b * 5;

        const int   ns = P.nsample[pidx];
        const float r2 = P.r2[pidx];
        const float* base = pcd + (size_t)b * NPTS * 3;

        if (t == 0) {
            int q;
            while ((q = __hip_atomic_load(&fps_idx[b * NPOINT + m_],
                                          __ATOMIC_RELAXED,
                                          __HIP_MEMORY_SCOPE_AGENT)) < 0)
                __builtin_amdgcn_s_sleep(16);
            s_qi[0] = q;
        }
        __syncthreads();
        const int qi = s_qi[0];
        float qx = base[3 * qi + 0], qy = base[3 * qi + 1], qz = base[3 * qi + 2];

        // ---- Phase A pass 1: ballot the wave's 8 sub-chunks of 64 points ----
        unsigned long long msk[8];
        int lbase[8];
        int run = 0;
        #pragma unroll 4
        for (int s = 0; s < 8; ++s) {
            int n = wave * 512 + s * 64 + lane;
            float x = base[3 * n + 0];
            float y = base[3 * n + 1];
            float z = base[3 * n + 2];
            float d2;
            {
#pragma clang fp contract(off)
                float dx = qx - x, dy = qy - y, dz = qz - z;
                float aa = dx * dx, bb2 = dy * dy, cc = dz * dz;
                d2 = (aa + bb2) + cc;
            }
            msk[s] = __ballot(d2 < r2);        // strict <, matches reference
            lbase[s] = run;
            run += __popcll(msk[s]);
        }
        if (lane == 0) s_wtot[wave] = run;
        __syncthreads();
        int Bw = 0, cnt = 0;
        #pragma unroll
        for (int j = 0; j < NWAVE; ++j) {
            int wj = s_wtot[j];
            cnt += wj;
            if (j < wave) Bw += wj;
        }
        int cntB = cnt < ns ? cnt : ns;        // real points kept
        const int npad = ns - cntB;

        // ---- Phase A pass 2: ordered compaction into LDS, w = |p|^2 ----
        #pragma unroll 4
        for (int s = 0; s < 8; ++s) {
            int gb = Bw + lbase[s];            // wave-uniform
            if (gb >= ns) break;
            unsigned long long mk = msk[s];
            bool in = (mk >> lane) & 1ull;
            int pos = gb + __popcll(mk & ((1ull << lane) - 1ull));
            if (in && pos < ns) {
                int n = wave * 512 + s * 64 + lane;
                float x = base[3 * n], y = base[3 * n + 1], z = base[3 * n + 2];
                float sq = fmaf(x, x, fmaf(y, y, z * z));
                gpts[pos] = make_float4(x, y, z, sq);
            }
        }
        __syncthreads();

        // ---- Phase B: each wave streams its eighth of j ----
        const int eighth = (cntB + 7) >> 3;
        const int j0 = wave * eighth;
        const int j1 = (j0 + eighth) < cntB ? (j0 + eighth) : cntB;
        const int nslot = (cntB + 63) >> 6;    // 1..7
        switch (nslot) {
            case 1: phaseB<1>(gpts, wres[wave], j0, j1, lane, cntB); break;
            case 2: phaseB<2>(gpts, wres[wave], j0, j1, lane, cntB); break;
            case 3: phaseB<3>(gpts, wres[wave], j0, j1, lane, cntB); break;
            case 4: phaseB<4>(gpts, wres[wave], j0, j1, lane, cntB); break;
            case 5: phaseB<5>(gpts, wres[wave], j0, j1, lane, cntB); break;
            case 6: phaseB<6>(gpts, wres[wave], j0, j1, lane, cntB); break;
            default: phaseB<7>(gpts, wres[wave], j0, j1, lane, cntB); break;
        }
        __syncthreads();

        // ---- Merge 8 waves' min2 pairs per i (exact tree); then sum sqrt ----
        float sum = 0.0f;
        for (int it = t; it < nslot * 64; it += FPS_T) {
            int i = it;                        // = s*64 + l
            if (i < cntB) {
                int s = it >> 6, l = it & 63;
                float2 e  = min2merge(wres[0][s][l], wres[1][s][l]);
                float2 f  = min2merge(wres[2][s][l], wres[3][s][l]);
                float2 g  = min2merge(wres[4][s][l], wres[5][s][l]);
                float2 h  = min2merge(wres[6][s][l], wres[7][s][l]);
                float2 ef = min2merge(e, f);
                float2 gh = min2merge(g, h);
                float m2v = fminf(fmaxf(ef.x, gh.x), fminf(ef.y, gh.y));
                float sq = gpts[i].w;
                float d2 = fmaxf(sq + m2v, 0.0f);
                // pads duplicate gpts[0] => i=0's nn is exactly 0 when npad>0
                if (!(i == 0 && npad > 0)) sum += sqrtf(d2);
            }
        }
        #pragma unroll
        for (int off = 32; off; off >>= 1) sum += __shfl_down(sum, off);
        if (lane == 0) s_part[wave] = sum;
        __syncthreads();
        if (t == 0) {
            float tot = 0.0f;
            #pragma unroll
            for (int j = 0; j < NWAVE; ++j) tot += s_part[j];
            tot += 0.1f * (float)ns;
            float u  = tot / (float)ns;
            float du = u - P.expect_len;
            partials[tau] = du * du / (P.expect_len + 0.1f) * P.wscale[pidx];
        }
        // no extra barrier needed: next round's first shared write (s_wtot)
        // races with nothing still being read from this round.
    }
}

// ---------------------------------------------------------------------------
// Fused kernel: 512 blocks x 512 threads, 2 blocks/CU x 256 CU co-resident
// by construction, so the worker spin cannot deadlock.
// ---------------------------------------------------------------------------
__global__ __launch_bounds__(FPS_T, 4) void fused_kernel(const float* __restrict__ pcd,
                                                         int* __restrict__ fps_idx,
                                                         float* __restrict__ partials,
                                                         LossParams P) {
    __shared__ __align__(16) char smem[SMEM_BYTES];
    if (blockIdx.x < 2) {
        fps_role(pcd, fps_idx, smem);
    } else {
        worker_role(pcd, fps_idx, partials, P, smem);
    }
}

// ---------------------------------------------------------------------------
// Kernel 3: sum the 2040 per-block partials -> d_out (no atomics anywhere).
// ---------------------------------------------------------------------------
__global__ __launch_bounds__(256) void reduce_kernel(const float* __restrict__ partials,
                                                     float* __restrict__ out) {
    const int t = threadIdx.x;
    __shared__ float sp[4];
    float s = 0.0f;
    for (int i = t; i < NPART; i += 256) s += partials[i];
    #pragma unroll
    for (int off = 32; off; off >>= 1) s += __shfl_down(s, off);
    if ((t & 63) == 0) sp[t >> 6] = s;
    __syncthreads();
    if (t == 0) out[0] = sp[0] + sp[1] + sp[2] + sp[3];
}

extern "C" void kernel_launch(void* const* d_in, const int* in_sizes, int n_in,
                              void* d_out, int out_size, void* d_ws, size_t ws_size,
                              hipStream_t stream) {
    const float* pcd = (const float*)d_in[0];
    const int B = in_sizes[0] / (NPTS * 3);   // = 2
    float* out = (float*)d_out;
    int*   fps = (int*)d_ws;                  // [0, NGROUP) ints
    float* partials = (float*)d_ws + NGROUP;  // [NGROUP, NGROUP+NPART) floats

    // sentinel: -1 means "index m not yet produced" (workspace persists
    // across graph replays, so this must run every invocation)
    hipMemsetAsync(fps, 0xFF, NGROUP * sizeof(int), stream);

    LossParams P;
    const double ps[NPCT] = {0.02, 0.04, 0.06, 0.08, 0.10};
    for (int i = 0; i < NPCT; ++i) {
        P.nsample[i] = (int)(NPTS * ps[i]);
        double r = std::sqrt(ps[i] * 1.0);
        P.r2[i] = (float)(r * r);
        double w = (ps[i] * 100.0) * (ps[i] * 100.0);
        P.wscale[i] = (float)(w / (double)(B * NPOINT * NPCT));
    }
    P.expect_len = (float)std::sqrt(3.14159265358979323846 / (double)NPTS);

    fused_kernel<<<dim3(2 + NWORK), dim3(FPS_T), 0, stream>>>(pcd, fps, partials, P);
    reduce_kernel<<<dim3(1), dim3(256), 0, stream>>>(partials, out);
}

// Round 9
// 189.779 us; speedup vs baseline: 1.1183x; 1.1183x over previous
//
#include <hip/hip_runtime.h>
#include <cmath>

#define NPTS 4096
#define NPOINT 204   // int(4096 * 0.05)
#define NPCT 5
#define MAXNS 409    // int(4096 * 0.10)
#define FPS_T 512    // threads per block (8 waves)
#define NGROUP 408   // B * NPOINT
#define NPART (NGROUP * NPCT)
#define MAXSLOT 7    // ceil(409/64)
#define NWAVE 8      // waves per block

// fused-launch geometry: 2 FPS blocks + 510 worker blocks = 512 blocks,
// ~66 KB LDS -> 2 blocks/CU x 256 CUs, all co-resident (R6-proven base:
// fused 135.0 / total 185.2 — best measured). R8's payload variant regressed
// (163.2) and is reverted.
#define NWORK  510
#define NROUND 4     // 510 * 4 = 2040 = NPART

// shared-memory union layout (bytes) — byte-identical to R6
#define SMEM_BYTES 65664          // fps: float4 pts[4096] (65536) + keys u64[2][8] (128)
#define KEYS_OFF   65536
#define WRES_OFF   6544           // grp: gpts float4[409] = 6544
#define WTOT_OFF   35216          //      wres float2[8][7][64] = 28672
#define SPART_OFF  35248          //      s_wtot int[8]
#define SQI_OFF    35280          //      s_part float[8]

typedef unsigned long long u64;
typedef float f32x2 __attribute__((ext_vector_type(2)));

struct LossParams {
    int   nsample[NPCT];
    float r2[NPCT];
    float wscale[NPCT];   // (p*100)^2 / (B*NPOINT*NPCT)
    float expect_len;
};

// ---------------- DPP wave64 reductions ------------------------------------
template <int CTRL>
__device__ __forceinline__ int dpp_imax(int v) {
    int t = __builtin_amdgcn_update_dpp(0, v, CTRL, 0xf, 0xf, true);
    return v > t ? v : t;
}
template <int CTRL>
__device__ __forceinline__ int dpp_imin(int v) {
    int t = __builtin_amdgcn_update_dpp(0x7fffffff, v, CTRL, 0xf, 0xf, false);
    return v < t ? v : t;
}
__device__ __forceinline__ int wave_max_i(int v) {
    v = dpp_imax<0x111>(v); v = dpp_imax<0x112>(v);
    v = dpp_imax<0x114>(v); v = dpp_imax<0x118>(v);
    v = dpp_imax<0x142>(v); v = dpp_imax<0x143>(v);
    return __builtin_amdgcn_readlane(v, 63);
}
__device__ __forceinline__ int wave_min_i(int v) {
    v = dpp_imin<0x111>(v); v = dpp_imin<0x112>(v);
    v = dpp_imin<0x114>(v); v = dpp_imin<0x118>(v);
    v = dpp_imin<0x142>(v); v = dpp_imin<0x143>(v);
    return __builtin_amdgcn_readlane(v, 63);
}
template <int CTRL>
__device__ __forceinline__ u64 dpp_u64max(u64 v) {
    int lo = (int)(unsigned)v;
    int hi = (int)(unsigned)(v >> 32);
    unsigned slo = (unsigned)__builtin_amdgcn_update_dpp(0, lo, CTRL, 0xf, 0xf, true);
    unsigned shi = (unsigned)__builtin_amdgcn_update_dpp(0, hi, CTRL, 0xf, 0xf, true);
    u64 o = ((u64)shi << 32) | slo;
    return v > o ? v : o;
}

// ---------------------------------------------------------------------------
// FPS role — byte-identical to R6 except ONE change: the intra-wave argmin-
// index step. wave_min_i's 6-stage DPP chain exists only to break ties in
// (bb == wmax). We ballot the tied lanes first; when exactly ONE lane is
// tied (the overwhelmingly common case — ties need exact FP equality at the
// max), its bi is fetched with a single variable-lane v_readlane (exact:
// a unique max lane IS the argmax). The DPP min chain remains as the
// fallback for multi-ties, so selected indices are bit-identical to R6 in
// ALL cases. Saves ~100-150 cy of dependent DPP per iteration.
// ---------------------------------------------------------------------------
__device__ void fps_role(const float* __restrict__ pcd,
                         int* __restrict__ fps_idx,
                         char* smem) {
#pragma clang fp contract(off)
    __builtin_amdgcn_s_setprio(3);
    float4* pts = reinterpret_cast<float4*>(smem);          // 64 KB
    u64 (*keys)[NWAVE] = reinterpret_cast<u64 (*)[NWAVE]>(smem + KEYS_OFF);

    const int b = blockIdx.x;
    const int t = threadIdx.x;
    const int wave = t >> 6, lane = t & 63;
    const float* base = pcd + (size_t)b * NPTS * 3;

    f32x2 X[4], Y[4], Z[4], D[4];
    #pragma unroll
    for (int q = 0; q < 4; ++q) {
        int n0 = (2 * q) * FPS_T + t;
        int n1 = (2 * q + 1) * FPS_T + t;
        float x0 = base[3 * n0 + 0], y0 = base[3 * n0 + 1], z0 = base[3 * n0 + 2];
        float x1 = base[3 * n1 + 0], y1 = base[3 * n1 + 1], z1 = base[3 * n1 + 2];
        pts[n0] = make_float4(x0, y0, z0, 0.0f);
        pts[n1] = make_float4(x1, y1, z1, 0.0f);
        X[q] = (f32x2){x0, x1};
        Y[q] = (f32x2){y0, y1};
        Z[q] = (f32x2){z0, z1};
        D[q] = (f32x2){1e10f, 1e10f};
    }
    int* out = fps_idx + b * NPOINT;
    if (t == 0)
        __hip_atomic_store(&out[0], 0, __ATOMIC_RELAXED, __HIP_MEMORY_SCOPE_AGENT);
    __syncthreads();

    float4 c = pts[0];
    for (int it = 1; it < NPOINT; ++it) {
        f32x2 cxx = (f32x2){c.x, c.x};
        f32x2 cyy = (f32x2){c.y, c.y};
        f32x2 czz = (f32x2){c.z, c.z};
        int bb = -1, bi = 0;
        #pragma unroll
        for (int q = 0; q < 4; ++q) {
            f32x2 dx = X[q] - cxx, dy = Y[q] - cyy, dz = Z[q] - czz;
            f32x2 d  = (dx * dx + dy * dy) + dz * dz;
            f32x2 dd = D[q];
            float d0 = fminf(dd.x, d.x);
            float d1 = fminf(dd.y, d.y);
            D[q] = (f32x2){d0, d1};
            int b0 = __float_as_int(d0);
            int b1 = __float_as_int(d1);
            if (b0 > bb) { bb = b0; bi = (2 * q) * FPS_T + t; }
            if (b1 > bb) { bb = b1; bi = (2 * q + 1) * FPS_T + t; }
        }
        int wmax = wave_max_i(bb);
        // --- fast argmin-index: unique max lane (common) -> 1 readlane ---
        u64 tied = __ballot(bb == wmax);
        int widx;
        if (__popcll(tied) == 1) {                    // wave-uniform branch
            int lsrc = (int)(__ffsll((long long)tied) - 1);
            widx = __builtin_amdgcn_readlane(bi, lsrc);
        } else {                                      // rare: exact tie-break
            int cand = (bb == wmax) ? bi : 0x7fffffff;
            widx = wave_min_i(cand);
        }
        if (lane == 0)
            keys[it & 1][wave] =
                ((u64)(unsigned)wmax << 32) | (unsigned)~(unsigned)widx;
        // LDS-only barrier (keys visibility needs lgkmcnt, not vmcnt drain)
        asm volatile("s_waitcnt lgkmcnt(0)" ::: "memory");
        __builtin_amdgcn_s_barrier();
        u64 kv = keys[it & 1][lane & 7];     // 8 wave-keys
        kv = dpp_u64max<0x111>(kv);
        kv = dpp_u64max<0x112>(kv);
        kv = dpp_u64max<0x114>(kv);
        unsigned lo7 = (unsigned)__builtin_amdgcn_readlane((int)(unsigned)kv, 7);
        int last = (int)~lo7;
        c = pts[last];
        if (t == 0)
            __hip_atomic_store(&out[it], last, __ATOMIC_RELAXED, __HIP_MEMORY_SCOPE_AGENT);
    }
}

// ---- Phase B worker: K i-slots/lane, j streamed over this wave's eighth ---
// min2 (smallest two incl. self) tracking via med3; exact reference k=2 KNN.
template <int K>
__device__ __forceinline__ void phaseB(const float4* __restrict__ gpts,
                                       float2 (*wres)[64],   // [MAXSLOT][64], this wave's slab
                                       int j0, int j1, int lane, int cntB) {
    float4 pi[K];
    float m1[K], m2[K];
    #pragma unroll
    for (int s = 0; s < K; ++s) {
        int idx = s * 64 + lane;
        pi[s] = gpts[idx < cntB ? idx : 0];   // dummy lanes skipped at merge
        m1[s] = 1e30f; m2[s] = 1e30f;
    }
    #pragma unroll 2
    for (int j = j0; j < j1; ++j) {
        float4 a = gpts[j];                   // wave-uniform broadcast read
        #pragma unroll
        for (int s = 0; s < K; ++s) {
            float tt = pi[s].x * a.x;
            tt = fmaf(pi[s].y, a.y, tt);
            tt = fmaf(pi[s].z, a.z, tt);
            float h = fmaf(-2.0f, tt, a.w);   // |a|^2 - 2<pi,a>
            m2[s] = __builtin_amdgcn_fmed3f(m1[s], m2[s], h);
            m1[s] = fminf(m1[s], h);
        }
    }
    #pragma unroll
    for (int s = 0; s < K; ++s) wres[s][lane] = (float2){m1[s], m2[s]};
}

// exact min2 merge of two (m1,m2) pairs — pure selection, no rounding
__device__ __forceinline__ float2 min2merge(float2 a, float2 b) {
    return (float2){fminf(a.x, b.x),
                    fminf(fmaxf(a.x, b.x), fminf(a.y, b.y))};
}

// ---------------------------------------------------------------------------
// Worker role: R6-proven static assignment, tau = w + round*510 (ascending m
// -> tasks unlock progressively while FPS runs). Byte-identical to R6.
// ---------------------------------------------------------------------------
__device__ void worker_role(const float* __restrict__ pcd,
                            int* __restrict__ fps_idx,
                            float* __restrict__ partials,
                            const LossParams& P, char* smem) {
    float4* gpts = reinterpret_cast<float4*>(smem);
    auto wres    = reinterpret_cast<float2 (*)[MAXSLOT][64]>(smem + WRES_OFF);
    int*   s_wtot = reinterpret_cast<int*>(smem + WTOT_OFF);
    float* s_part = reinterpret_cast<float*>(smem + SPART_OFF);
    int*   s_qi   = reinterpret_cast<int*>(smem + SQI_OFF);

    const int w = blockIdx.x - 2;
    const int t = threadIdx.x;
    const int wave = t >> 6, lane = t & 63;

    for (int round = 0; round < NROUND; ++round) {
        const int tau  = w + round * NWORK;          // 0 .. NPART-1, each once
        const int m_   = tau / 10;                   // group row (unlock order)
        const int rem  = tau - m_ * 10;
        const int b    = rem / 5;
        const int pidx = rem - b * 5;

        const int   ns = P.nsample[pidx];
        const float r2 = P.r2[pidx];
        const float* base = pcd + (size_t)b * NPTS * 3;

        if (t == 0) {
            int q;
            while ((q = __hip_atomic_load(&fps_idx[b * NPOINT + m_],
                                          __ATOMIC_RELAXED,
                                          __HIP_MEMORY_SCOPE_AGENT)) < 0)
                __builtin_amdgcn_s_sleep(16);
            s_qi[0] = q;
        }
        __syncthreads();
        const int qi = s_qi[0];
        float qx = base[3 * qi + 0], qy = base[3 * qi + 1], qz = base[3 * qi + 2];

        // ---- Phase A pass 1: ballot the wave's 8 sub-chunks of 64 points ----
        unsigned long long msk[8];
        int lbase[8];
        int run = 0;
        #pragma unroll 4
        for (int s = 0; s < 8; ++s) {
            int n = wave * 512 + s * 64 + lane;
            float x = base[3 * n + 0];
            float y = base[3 * n + 1];
            float z = base[3 * n + 2];
            float d2;
            {
#pragma clang fp contract(off)
                float dx = qx - x, dy = qy - y, dz = qz - z;
                float aa = dx * dx, bb2 = dy * dy, cc = dz * dz;
                d2 = (aa + bb2) + cc;
            }
            msk[s] = __ballot(d2 < r2);        // strict <, matches reference
            lbase[s] = run;
            run += __popcll(msk[s]);
        }
        if (lane == 0) s_wtot[wave] = run;
        __syncthreads();
        int Bw = 0, cnt = 0;
        #pragma unroll
        for (int j = 0; j < NWAVE; ++j) {
            int wj = s_wtot[j];
            cnt += wj;
            if (j < wave) Bw += wj;
        }
        int cntB = cnt < ns ? cnt : ns;        // real points kept
        const int npad = ns - cntB;

        // ---- Phase A pass 2: ordered compaction into LDS, w = |p|^2 ----
        #pragma unroll 4
        for (int s = 0; s < 8; ++s) {
            int gb = Bw + lbase[s];            // wave-uniform
            if (gb >= ns) break;
            unsigned long long mk = msk[s];
            bool in = (mk >> lane) & 1ull;
            int pos = gb + __popcll(mk & ((1ull << lane) - 1ull));
            if (in && pos < ns) {
                int n = wave * 512 + s * 64 + lane;
                float x = base[3 * n], y = base[3 * n + 1], z = base[3 * n + 2];
                float sq = fmaf(x, x, fmaf(y, y, z * z));
                gpts[pos] = make_float4(x, y, z, sq);
            }
        }
        __syncthreads();

        // ---- Phase B: each wave streams its eighth of j ----
        const int eighth = (cntB + 7) >> 3;
        const int j0 = wave * eighth;
        const int j1 = (j0 + eighth) < cntB ? (j0 + eighth) : cntB;
        const int nslot = (cntB + 63) >> 6;    // 1..7
        switch (nslot) {
            case 1: phaseB<1>(gpts, wres[wave], j0, j1, lane, cntB); break;
            case 2: phaseB<2>(gpts, wres[wave], j0, j1, lane, cntB); break;
            case 3: phaseB<3>(gpts, wres[wave], j0, j1, lane, cntB); break;
            case 4: phaseB<4>(gpts, wres[wave], j0, j1, lane, cntB); break;
            case 5: phaseB<5>(gpts, wres[wave], j0, j1, lane, cntB); break;
            case 6: phaseB<6>(gpts, wres[wave], j0, j1, lane, cntB); break;
            default: phaseB<7>(gpts, wres[wave], j0, j1, lane, cntB); break;
        }
        __syncthreads();

        // ---- Merge 8 waves' min2 pairs per i (exact tree); then sum sqrt ----
        float sum = 0.0f;
        for (int it = t; it < nslot * 64; it += FPS_T) {
            int i = it;                        // = s*64 + l
            if (i < cntB) {
                int s = it >> 6, l = it & 63;
                float2 e  = min2merge(wres[0][s][l], wres[1][s][l]);
                float2 f  = min2merge(wres[2][s][l], wres[3][s][l]);
                float2 g  = min2merge(wres[4][s][l], wres[5][s][l]);
                float2 h  = min2merge(wres[6][s][l], wres[7][s][l]);
                float2 ef = min2merge(e, f);
                float2 gh = min2merge(g, h);
                float m2v = fminf(fmaxf(ef.x, gh.x), fminf(ef.y, gh.y));
                float sq = gpts[i].w;
                float d2 = fmaxf(sq + m2v, 0.0f);
                // pads duplicate gpts[0] => i=0's nn is exactly 0 when npad>0
                if (!(i == 0 && npad > 0)) sum += sqrtf(d2);
            }
        }
        #pragma unroll
        for (int off = 32; off; off >>= 1) sum += __shfl_down(sum, off);
        if (lane == 0) s_part[wave] = sum;
        __syncthreads();
        if (t == 0) {
            float tot = 0.0f;
            #pragma unroll
            for (int j = 0; j < NWAVE; ++j) tot += s_part[j];
            tot += 0.1f * (float)ns;
            float u  = tot / (float)ns;
            float du = u - P.expect_len;
            partials[tau] = du * du / (P.expect_len + 0.1f) * P.wscale[pidx];
        }
        // no extra barrier needed: next round's first shared write (s_wtot)
        // races with nothing still being read from this round.
    }
}

// ---------------------------------------------------------------------------
// Fused kernel: 512 blocks x 512 threads, 2 blocks/CU x 256 CU co-resident
// by construction, so the worker spin cannot deadlock.
// ---------------------------------------------------------------------------
__global__ __launch_bounds__(FPS_T, 4) void fused_kernel(const float* __restrict__ pcd,
                                                         int* __restrict__ fps_idx,
                                                         float* __restrict__ partials,
                                                         LossParams P) {
    __shared__ __align__(16) char smem[SMEM_BYTES];
    if (blockIdx.x < 2) {
        fps_role(pcd, fps_idx, smem);
    } else {
        worker_role(pcd, fps_idx, partials, P, smem);
    }
}

// ---------------------------------------------------------------------------
// Kernel 3: sum the 2040 per-block partials -> d_out (no atomics anywhere).
// ---------------------------------------------------------------------------
__global__ __launch_bounds__(256) void reduce_kernel(const float* __restrict__ partials,
                                                     float* __restrict__ out) {
    const int t = threadIdx.x;
    __shared__ float sp[4];
    float s = 0.0f;
    for (int i = t; i < NPART; i += 256) s += partials[i];
    #pragma unroll
    for (int off = 32; off; off >>= 1) s += __shfl_down(s, off);
    if ((t & 63) == 0) sp[t >> 6] = s;
    __syncthreads();
    if (t == 0) out[0] = sp[0] + sp[1] + sp[2] + sp[3];
}

extern "C" void kernel_launch(void* const* d_in, const int* in_sizes, int n_in,
                              void* d_out, int out_size, void* d_ws, size_t ws_size,
                              hipStream_t stream) {
    const float* pcd = (const float*)d_in[0];
    const int B = in_sizes[0] / (NPTS * 3);   // = 2
    float* out = (float*)d_out;
    int*   fps = (int*)d_ws;                  // [0, NGROUP) ints
    float* partials = (float*)d_ws + NGROUP;  // [NGROUP, NGROUP+NPART) floats

    // sentinel: -1 means "index m not yet produced" (workspace persists
    // across graph replays, so this must run every invocation)
    hipMemsetAsync(fps, 0xFF, NGROUP * sizeof(int), stream);

    LossParams P;
    const double ps[NPCT] = {0.02, 0.04, 0.06, 0.08, 0.10};
    for (int i = 0; i < NPCT; ++i) {
        P.nsample[i] = (int)(NPTS * ps[i]);
        double r = std::sqrt(ps[i] * 1.0);
        P.r2[i] = (float)(r * r);
        double w = (ps[i] * 100.0) * (ps[i] * 100.0);
        P.wscale[i] = (float)(w / (double)(B * NPOINT * NPCT));
    }
    P.expect_len = (float)std::sqrt(3.14159265358979323846 / (double)NPTS);

    fused_kernel<<<dim3(2 + NWORK), dim3(FPS_T), 0, stream>>>(pcd, fps, partials, P);
    reduce_kernel<<<dim3(1), dim3(256), 0, stream>>>(partials, out);
}

// Round 10
// 185.605 us; speedup vs baseline: 1.1434x; 1.0225x over previous
//
#include <hip/hip_runtime.h>
#include <cmath>

#define NPTS 4096
#define NPOINT 204   // int(4096 * 0.05)
#define NPCT 5
#define MAXNS 409    // int(4096 * 0.10)
#define FPS_T 512    // threads per block (8 waves)
#define NGROUP 408   // B * NPOINT
#define NPART (NGROUP * NPCT)
#define MAXSLOT 7    // ceil(409/64)
#define NWAVE 8      // waves per block

// fused-launch geometry: 2 FPS blocks + 510 worker blocks = 512 blocks.
// 66 KB LDS -> 2 blocks/CU x 256 CUs, all co-resident (R6-proven best:
// fused 135.0 us / total 185.2 us). This is a byte-exact revert to R6 —
// R7/R8/R9 probes all regressed and are dropped.
#define NWORK  510
#define NROUND 4     // 510 * 4 = 2040 = NPART

// shared-memory union layout (bytes)
#define SMEM_BYTES 65664          // fps: float4 pts[4096] (65536) + keys u64[2][8] (128)
#define KEYS_OFF   65536
#define WRES_OFF   6544           // grp: gpts float4[409] = 6544
#define WTOT_OFF   35216          //      wres float2[8][7][64] = 28672
#define SPART_OFF  35248          //      s_wtot int[8]
#define SQI_OFF    35280          //      s_part float[8]

typedef unsigned long long u64;
typedef float f32x2 __attribute__((ext_vector_type(2)));

struct LossParams {
    int   nsample[NPCT];
    float r2[NPCT];
    float wscale[NPCT];   // (p*100)^2 / (B*NPOINT*NPCT)
    float expect_len;
};

// ---------------- DPP wave64 reductions ------------------------------------
template <int CTRL>
__device__ __forceinline__ int dpp_imax(int v) {
    int t = __builtin_amdgcn_update_dpp(0, v, CTRL, 0xf, 0xf, true);
    return v > t ? v : t;
}
template <int CTRL>
__device__ __forceinline__ int dpp_imin(int v) {
    int t = __builtin_amdgcn_update_dpp(0x7fffffff, v, CTRL, 0xf, 0xf, false);
    return v < t ? v : t;
}
__device__ __forceinline__ int wave_max_i(int v) {
    v = dpp_imax<0x111>(v); v = dpp_imax<0x112>(v);
    v = dpp_imax<0x114>(v); v = dpp_imax<0x118>(v);
    v = dpp_imax<0x142>(v); v = dpp_imax<0x143>(v);
    return __builtin_amdgcn_readlane(v, 63);
}
__device__ __forceinline__ int wave_min_i(int v) {
    v = dpp_imin<0x111>(v); v = dpp_imin<0x112>(v);
    v = dpp_imin<0x114>(v); v = dpp_imin<0x118>(v);
    v = dpp_imin<0x142>(v); v = dpp_imin<0x143>(v);
    return __builtin_amdgcn_readlane(v, 63);
}
template <int CTRL>
__device__ __forceinline__ u64 dpp_u64max(u64 v) {
    int lo = (int)(unsigned)v;
    int hi = (int)(unsigned)(v >> 32);
    unsigned slo = (unsigned)__builtin_amdgcn_update_dpp(0, lo, CTRL, 0xf, 0xf, true);
    unsigned shi = (unsigned)__builtin_amdgcn_update_dpp(0, hi, CTRL, 0xf, 0xf, true);
    u64 o = ((u64)shi << 32) | slo;
    return v > o ? v : o;
}

// ---------------------------------------------------------------------------
// FPS role — R6-proven: 512 thr, 8 pts/lane, scan argmax, dual DPP chains,
// lgkmcnt-only barrier, 8-key cross-wave reduce, keys ping-pong.
// ---------------------------------------------------------------------------
__device__ void fps_role(const float* __restrict__ pcd,
                         int* __restrict__ fps_idx,
                         char* smem) {
#pragma clang fp contract(off)
    __builtin_amdgcn_s_setprio(3);
    float4* pts = reinterpret_cast<float4*>(smem);          // 64 KB
    u64 (*keys)[NWAVE] = reinterpret_cast<u64 (*)[NWAVE]>(smem + KEYS_OFF);

    const int b = blockIdx.x;
    const int t = threadIdx.x;
    const int wave = t >> 6, lane = t & 63;
    const float* base = pcd + (size_t)b * NPTS * 3;

    f32x2 X[4], Y[4], Z[4], D[4];
    #pragma unroll
    for (int q = 0; q < 4; ++q) {
        int n0 = (2 * q) * FPS_T + t;
        int n1 = (2 * q + 1) * FPS_T + t;
        float x0 = base[3 * n0 + 0], y0 = base[3 * n0 + 1], z0 = base[3 * n0 + 2];
        float x1 = base[3 * n1 + 0], y1 = base[3 * n1 + 1], z1 = base[3 * n1 + 2];
        pts[n0] = make_float4(x0, y0, z0, 0.0f);
        pts[n1] = make_float4(x1, y1, z1, 0.0f);
        X[q] = (f32x2){x0, x1};
        Y[q] = (f32x2){y0, y1};
        Z[q] = (f32x2){z0, z1};
        D[q] = (f32x2){1e10f, 1e10f};
    }
    int* out = fps_idx + b * NPOINT;
    if (t == 0)
        __hip_atomic_store(&out[0], 0, __ATOMIC_RELAXED, __HIP_MEMORY_SCOPE_AGENT);
    __syncthreads();

    float4 c = pts[0];
    for (int it = 1; it < NPOINT; ++it) {
        f32x2 cxx = (f32x2){c.x, c.x};
        f32x2 cyy = (f32x2){c.y, c.y};
        f32x2 czz = (f32x2){c.z, c.z};
        int bb = -1, bi = 0;
        #pragma unroll
        for (int q = 0; q < 4; ++q) {
            f32x2 dx = X[q] - cxx, dy = Y[q] - cyy, dz = Z[q] - czz;
            f32x2 d  = (dx * dx + dy * dy) + dz * dz;
            f32x2 dd = D[q];
            float d0 = fminf(dd.x, d.x);
            float d1 = fminf(dd.y, d.y);
            D[q] = (f32x2){d0, d1};
            int b0 = __float_as_int(d0);
            int b1 = __float_as_int(d1);
            if (b0 > bb) { bb = b0; bi = (2 * q) * FPS_T + t; }
            if (b1 > bb) { bb = b1; bi = (2 * q + 1) * FPS_T + t; }
        }
        int wmax = wave_max_i(bb);
        int cand = (bb == wmax) ? bi : 0x7fffffff;
        int widx = wave_min_i(cand);
        if (lane == 0)
            keys[it & 1][wave] =
                ((u64)(unsigned)wmax << 32) | (unsigned)~(unsigned)widx;
        // LDS-only barrier (keys visibility needs lgkmcnt, not vmcnt drain)
        asm volatile("s_waitcnt lgkmcnt(0)" ::: "memory");
        __builtin_amdgcn_s_barrier();
        u64 kv = keys[it & 1][lane & 7];     // 8 wave-keys
        kv = dpp_u64max<0x111>(kv);
        kv = dpp_u64max<0x112>(kv);
        kv = dpp_u64max<0x114>(kv);
        unsigned lo7 = (unsigned)__builtin_amdgcn_readlane((int)(unsigned)kv, 7);
        int last = (int)~lo7;
        c = pts[last];
        if (t == 0)
            __hip_atomic_store(&out[it], last, __ATOMIC_RELAXED, __HIP_MEMORY_SCOPE_AGENT);
    }
}

// ---- Phase B worker: K i-slots/lane, j streamed over this wave's eighth ---
// min2 (smallest two incl. self) tracking via med3; exact reference k=2 KNN.
template <int K>
__device__ __forceinline__ void phaseB(const float4* __restrict__ gpts,
                                       float2 (*wres)[64],   // [MAXSLOT][64], this wave's slab
                                       int j0, int j1, int lane, int cntB) {
    float4 pi[K];
    float m1[K], m2[K];
    #pragma unroll
    for (int s = 0; s < K; ++s) {
        int idx = s * 64 + lane;
        pi[s] = gpts[idx < cntB ? idx : 0];   // dummy lanes skipped at merge
        m1[s] = 1e30f; m2[s] = 1e30f;
    }
    #pragma unroll 2
    for (int j = j0; j < j1; ++j) {
        float4 a = gpts[j];                   // wave-uniform broadcast read
        #pragma unroll
        for (int s = 0; s < K; ++s) {
            float tt = pi[s].x * a.x;
            tt = fmaf(pi[s].y, a.y, tt);
            tt = fmaf(pi[s].z, a.z, tt);
            float h = fmaf(-2.0f, tt, a.w);   // |a|^2 - 2<pi,a>
            m2[s] = __builtin_amdgcn_fmed3f(m1[s], m2[s], h);
            m1[s] = fminf(m1[s], h);
        }
    }
    #pragma unroll
    for (int s = 0; s < K; ++s) wres[s][lane] = (float2){m1[s], m2[s]};
}

// exact min2 merge of two (m1,m2) pairs — pure selection, no rounding
__device__ __forceinline__ float2 min2merge(float2 a, float2 b) {
    return (float2){fminf(a.x, b.x),
                    fminf(fmaxf(a.x, b.x), fminf(a.y, b.y))};
}

// ---------------------------------------------------------------------------
// Worker role: R6-proven static assignment, tau = w + round*510 (ascending m
// -> tasks unlock progressively while FPS runs).
// ---------------------------------------------------------------------------
__device__ void worker_role(const float* __restrict__ pcd,
                            int* __restrict__ fps_idx,
                            float* __restrict__ partials,
                            const LossParams& P, char* smem) {
    float4* gpts = reinterpret_cast<float4*>(smem);
    auto wres    = reinterpret_cast<float2 (*)[MAXSLOT][64]>(smem + WRES_OFF);
    int*   s_wtot = reinterpret_cast<int*>(smem + WTOT_OFF);
    float* s_part = reinterpret_cast<float*>(smem + SPART_OFF);
    int*   s_qi   = reinterpret_cast<int*>(smem + SQI_OFF);

    const int w = blockIdx.x - 2;
    const int t = threadIdx.x;
    const int wave = t >> 6, lane = t & 63;

    for (int round = 0; round < NROUND; ++round) {
        const int tau  = w + round * NWORK;          // 0 .. NPART-1, each once
        const int m_   = tau / 10;                   // group row (unlock order)
        const int rem  = tau - m_ * 10;
        const int b    = rem / 5;
        const int pidx = rem - b * 5;

        const int   ns = P.nsample[pidx];
        const float r2 = P.r2[pidx];
        const float* base = pcd + (size_t)b * NPTS * 3;

        if (t == 0) {
            int q;
            while ((q = __hip_atomic_load(&fps_idx[b * NPOINT + m_],
                                          __ATOMIC_RELAXED,
                                          __HIP_MEMORY_SCOPE_AGENT)) < 0)
                __builtin_amdgcn_s_sleep(16);
            s_qi[0] = q;
        }
        __syncthreads();
        const int qi = s_qi[0];
        float qx = base[3 * qi + 0], qy = base[3 * qi + 1], qz = base[3 * qi + 2];

        // ---- Phase A pass 1: ballot the wave's 8 sub-chunks of 64 points ----
        unsigned long long msk[8];
        int lbase[8];
        int run = 0;
        #pragma unroll 4
        for (int s = 0; s < 8; ++s) {
            int n = wave * 512 + s * 64 + lane;
            float x = base[3 * n + 0];
            float y = base[3 * n + 1];
            float z = base[3 * n + 2];
            float d2;
            {
#pragma clang fp contract(off)
                float dx = qx - x, dy = qy - y, dz = qz - z;
                float aa = dx * dx, bb2 = dy * dy, cc = dz * dz;
                d2 = (aa + bb2) + cc;
            }
            msk[s] = __ballot(d2 < r2);        // strict <, matches reference
            lbase[s] = run;
            run += __popcll(msk[s]);
        }
        if (lane == 0) s_wtot[wave] = run;
        __syncthreads();
        int Bw = 0, cnt = 0;
        #pragma unroll
        for (int j = 0; j < NWAVE; ++j) {
            int wj = s_wtot[j];
            cnt += wj;
            if (j < wave) Bw += wj;
        }
        int cntB = cnt < ns ? cnt : ns;        // real points kept
        const int npad = ns - cntB;

        // ---- Phase A pass 2: ordered compaction into LDS, w = |p|^2 ----
        #pragma unroll 4
        for (int s = 0; s < 8; ++s) {
            int gb = Bw + lbase[s];            // wave-uniform
            if (gb >= ns) break;
            unsigned long long mk = msk[s];
            bool in = (mk >> lane) & 1ull;
            int pos = gb + __popcll(mk & ((1ull << lane) - 1ull));
            if (in && pos < ns) {
                int n = wave * 512 + s * 64 + lane;
                float x = base[3 * n], y = base[3 * n + 1], z = base[3 * n + 2];
                float sq = fmaf(x, x, fmaf(y, y, z * z));
                gpts[pos] = make_float4(x, y, z, sq);
            }
        }
        __syncthreads();

        // ---- Phase B: each wave streams its eighth of j ----
        const int eighth = (cntB + 7) >> 3;
        const int j0 = wave * eighth;
        const int j1 = (j0 + eighth) < cntB ? (j0 + eighth) : cntB;
        const int nslot = (cntB + 63) >> 6;    // 1..7
        switch (nslot) {
            case 1: phaseB<1>(gpts, wres[wave], j0, j1, lane, cntB); break;
            case 2: phaseB<2>(gpts, wres[wave], j0, j1, lane, cntB); break;
            case 3: phaseB<3>(gpts, wres[wave], j0, j1, lane, cntB); break;
            case 4: phaseB<4>(gpts, wres[wave], j0, j1, lane, cntB); break;
            case 5: phaseB<5>(gpts, wres[wave], j0, j1, lane, cntB); break;
            case 6: phaseB<6>(gpts, wres[wave], j0, j1, lane, cntB); break;
            default: phaseB<7>(gpts, wres[wave], j0, j1, lane, cntB); break;
        }
        __syncthreads();

        // ---- Merge 8 waves' min2 pairs per i (exact tree); then sum sqrt ----
        float sum = 0.0f;
        for (int it = t; it < nslot * 64; it += FPS_T) {
            int i = it;                        // = s*64 + l
            if (i < cntB) {
                int s = it >> 6, l = it & 63;
                float2 e  = min2merge(wres[0][s][l], wres[1][s][l]);
                float2 f  = min2merge(wres[2][s][l], wres[3][s][l]);
                float2 g  = min2merge(wres[4][s][l], wres[5][s][l]);
                float2 h  = min2merge(wres[6][s][l], wres[7][s][l]);
                float2 ef = min2merge(e, f);
                float2 gh = min2merge(g, h);
                float m2v = fminf(fmaxf(ef.x, gh.x), fminf(ef.y, gh.y));
                float sq = gpts[i].w;
                float d2 = fmaxf(sq + m2v, 0.0f);
                // pads duplicate gpts[0] => i=0's nn is exactly 0 when npad>0
                if (!(i == 0 && npad > 0)) sum += sqrtf(d2);
            }
        }
        #pragma unroll
        for (int off = 32; off; off >>= 1) sum += __shfl_down(sum, off);
        if (lane == 0) s_part[wave] = sum;
        __syncthreads();
        if (t == 0) {
            float tot = 0.0f;
            #pragma unroll
            for (int j = 0; j < NWAVE; ++j) tot += s_part[j];
            tot += 0.1f * (float)ns;
            float u  = tot / (float)ns;
            float du = u - P.expect_len;
            partials[tau] = du * du / (P.expect_len + 0.1f) * P.wscale[pidx];
        }
        // no extra barrier needed: next round's first shared write (s_wtot)
        // races with nothing still being read from this round.
    }
}

// ---------------------------------------------------------------------------
// Fused kernel: 512 blocks x 512 threads, 2 blocks/CU x 256 CU co-resident
// by construction, so the worker spin cannot deadlock.
// ---------------------------------------------------------------------------
__global__ __launch_bounds__(FPS_T, 4) void fused_kernel(const float* __restrict__ pcd,
                                                         int* __restrict__ fps_idx,
                                                         float* __restrict__ partials,
                                                         LossParams P) {
    __shared__ __align__(16) char smem[SMEM_BYTES];
    if (blockIdx.x < 2) {
        fps_role(pcd, fps_idx, smem);
    } else {
        worker_role(pcd, fps_idx, partials, P, smem);
    }
}

// ---------------------------------------------------------------------------
// Kernel 3: sum the 2040 per-block partials -> d_out (no atomics anywhere).
// ---------------------------------------------------------------------------
__global__ __launch_bounds__(256) void reduce_kernel(const float* __restrict__ partials,
                                                     float* __restrict__ out) {
    const int t = threadIdx.x;
    __shared__ float sp[4];
    float s = 0.0f;
    for (int i = t; i < NPART; i += 256) s += partials[i];
    #pragma unroll
    for (int off = 32; off; off >>= 1) s += __shfl_down(s, off);
    if ((t & 63) == 0) sp[t >> 6] = s;
    __syncthreads();
    if (t == 0) out[0] = sp[0] + sp[1] + sp[2] + sp[3];
}

extern "C" void kernel_launch(void* const* d_in, const int* in_sizes, int n_in,
                              void* d_out, int out_size, void* d_ws, size_t ws_size,
                              hipStream_t stream) {
    const float* pcd = (const float*)d_in[0];
    const int B = in_sizes[0] / (NPTS * 3);   // = 2
    float* out = (float*)d_out;
    int*   fps = (int*)d_ws;                  // [0, NGROUP) ints
    float* partials = (float*)d_ws + NGROUP;  // [NGROUP, NGROUP+NPART) floats

    // sentinel: -1 means "index m not yet produced" (workspace persists
    // across graph replays, so this must run every invocation)
    hipMemsetAsync(fps, 0xFF, NGROUP * sizeof(int), stream);

    LossParams P;
    const double ps[NPCT] = {0.02, 0.04, 0.06, 0.08, 0.10};
    for (int i = 0; i < NPCT; ++i) {
        P.nsample[i] = (int)(NPTS * ps[i]);
        double r = std::sqrt(ps[i] * 1.0);
        P.r2[i] = (float)(r * r);
        double w = (ps[i] * 100.0) * (ps[i] * 100.0);
        P.wscale[i] = (float)(w / (double)(B * NPOINT * NPCT));
    }
    P.expect_len = (float)std::sqrt(3.14159265358979323846 / (double)NPTS);

    fused_kernel<<<dim3(2 + NWORK), dim3(FPS_T), 0, stream>>>(pcd, fps, partials, P);
    reduce_kernel<<<dim3(1), dim3(256), 0, stream>>>(partials, out);
}